// Round 1
// baseline (448.033 us; speedup 1.0000x reference)
//
#include <hip/hip_runtime.h>
#include <math.h>

// Net_Without_GINEgPool: GATConv(32,128,h=4) + TopKPooling(0.8) + max/mean pool + MLP head.
// Pipeline: prep (fold att into 32x4) -> h=x@W + a_s/a_d -> CSR by dst (hist/scan/fill)
//           -> per-node softmax+aggregate -> topk by exact rank -> pool -> MLP+log_softmax.

#define N_NODES 32000
#define B_GRAPHS 32
#define NPG 1000            // nodes per graph
#define DEG 10
#define E_EDGES (N_NODES*DEG)
#define HD 512
#define F_IN 32
#define KKEEP 800
#define SLOPE 0.2f

// ---------------- prep: Ws/Wd = W folded with att vectors; inv-norm of topk_w ----------------
__global__ void prep_kernel(const float* __restrict__ W, const float* __restrict__ att_src,
                            const float* __restrict__ att_dst, const float* __restrict__ topk_w,
                            float* __restrict__ Ws, float* __restrict__ Wd, float* __restrict__ misc)
{
    int tid = threadIdx.x; // 256
    if (tid < 128) {
        int f = tid >> 2, hh = tid & 3;
        float s1 = 0.f, s2 = 0.f;
        for (int d = 0; d < 128; ++d) {
            float w = W[f*HD + hh*128 + d];
            s1 = fmaf(w, att_src[hh*128 + d], s1);
            s2 = fmaf(w, att_dst[hh*128 + d], s2);
        }
        Ws[f*4+hh] = s1;
        Wd[f*4+hh] = s2;
    }
    __shared__ float red[256];
    float tw0 = topk_w[tid], tw1 = topk_w[tid+256];
    red[tid] = tw0*tw0 + tw1*tw1;
    __syncthreads();
    for (int s = 128; s > 0; s >>= 1) { if (tid < s) red[tid] += red[tid+s]; __syncthreads(); }
    if (tid == 0) misc[0] = 1.0f / sqrtf(red[0]);
}

// ---------------- h = x @ W  [N,512]; a_s = x @ Ws, a_d = x @ Wd  [N,4] ----------------
#define NPB 16
__global__ __launch_bounds__(256) void compute_h_kernel(
    const float* __restrict__ x, const float* __restrict__ W,
    const float* __restrict__ Ws, const float* __restrict__ Wd,
    float* __restrict__ h, float* __restrict__ a_s, float* __restrict__ a_d)
{
    __shared__ float sW[F_IN*HD];   // 64 KB
    int tid = threadIdx.x;          // 256
    int n0 = blockIdx.x * NPB;
    for (int i = tid; i < F_IN*HD; i += 256) sW[i] = W[i];
    __syncthreads();
    for (int n = 0; n < NPB; ++n) {
        const float* xr = x + (size_t)(n0+n)*F_IN;
        float acc0 = 0.f, acc1 = 0.f;
        #pragma unroll
        for (int f = 0; f < F_IN; ++f) {
            float xv = xr[f];   // wave-uniform broadcast, L1-hit
            acc0 = fmaf(xv, sW[f*HD + tid], acc0);
            acc1 = fmaf(xv, sW[f*HD + tid + 256], acc1);
        }
        h[(size_t)(n0+n)*HD + tid] = acc0;
        h[(size_t)(n0+n)*HD + tid + 256] = acc1;
    }
    if (tid < 128) {
        int which = tid >> 6;      // 0 -> a_s, 1 -> a_d
        int u = tid & 63;
        int n = u >> 2, hh = u & 3;
        const float* Wx = which ? Wd : Ws;
        const float* xr = x + (size_t)(n0+n)*F_IN;
        float s = 0.f;
        #pragma unroll
        for (int f = 0; f < F_IN; ++f) s = fmaf(xr[f], Wx[f*4+hh], s);
        if (which) a_d[(size_t)(n0+n)*4 + hh] = s;
        else       a_s[(size_t)(n0+n)*4 + hh] = s;
    }
}

// ---------------- CSR build ----------------
__global__ void hist_kernel(const int* __restrict__ dst, int* __restrict__ counts)
{
    int i = blockIdx.x*blockDim.x + threadIdx.x;
    int stride = gridDim.x*blockDim.x;
    for (; i < E_EDGES; i += stride) atomicAdd(&counts[dst[i]], 1);
}

__global__ void scan_kernel(const int* __restrict__ counts, int* __restrict__ offsets,
                            int* __restrict__ cursor)
{
    __shared__ int sdata[1024];
    int tid = threadIdx.x;
    int running = 0;
    for (int base = 0; base < N_NODES; base += 1024) {
        int i = base + tid;
        int v = (i < N_NODES) ? counts[i] : 0;
        sdata[tid] = v;
        __syncthreads();
        for (int offt = 1; offt < 1024; offt <<= 1) {
            int t = (tid >= offt) ? sdata[tid - offt] : 0;
            __syncthreads();
            sdata[tid] += t;
            __syncthreads();
        }
        int incl = sdata[tid];
        int total = sdata[1023];
        if (i < N_NODES) { int o = running + incl - v; offsets[i] = o; cursor[i] = o; }
        running += total;
        __syncthreads();
    }
    if (tid == 0) offsets[N_NODES] = running;
}

__global__ void fill_kernel(const int* __restrict__ dst, int* __restrict__ cursor,
                            int* __restrict__ csr_eid)
{
    int i = blockIdx.x*blockDim.x + threadIdx.x;
    int stride = gridDim.x*blockDim.x;
    for (; i < E_EDGES; i += stride) {
        int p = atomicAdd(&cursor[dst[i]], 1);
        csr_eid[p] = i;
    }
}

// ---------------- per-dst-node GAT softmax + aggregate + relu + score ----------------
__global__ __launch_bounds__(256) void gat_agg_kernel(
    const float* __restrict__ h, const float* __restrict__ a_s, const float* __restrict__ a_d,
    const int* __restrict__ offsets, const int* __restrict__ csr_eid, const int* __restrict__ esrc,
    const float* __restrict__ bias, const float* __restrict__ topk_w, const float* __restrict__ misc,
    float* __restrict__ x1, float* __restrict__ scores)
{
    int node = blockIdx.x;
    int tid = threadIdx.x;
    int beg = offsets[node];
    int deg = offsets[node+1] - beg;   // real in-edges; +1 self loop appended last

    __shared__ int   s_eid[64];
    __shared__ float s_m[4], s_den[4], s_ad[4];
    __shared__ float s_alpha[32][4];
    __shared__ int   s_csrc[32];
    __shared__ float s_red[4];

    bool cached = (deg <= 64);
    if (cached && tid < deg) s_eid[tid] = csr_eid[beg + tid];
    if (tid < 4) s_ad[tid] = a_d[(size_t)node*4 + tid];
    __syncthreads();
    // sort edge ids for deterministic FP summation order (fill is atomic-ordered)
    if (cached && tid == 0) {
        for (int i = 1; i < deg; ++i) {
            int key = s_eid[i]; int j = i-1;
            while (j >= 0 && s_eid[j] > key) { s_eid[j+1] = s_eid[j]; --j; }
            s_eid[j+1] = key;
        }
    }
    __syncthreads();

    // Phase 1 (wave 0): per-head max and softmax denominator over deg+1 edges
    if (tid < 64) {
        int lane = tid;
        int hh = lane & 3;
        float ad = s_ad[hh];
        float m = -INFINITY;
        for (int base = 0; base <= deg; base += 16) {
            int e = base + (lane >> 2);
            float v = -INFINITY;
            if (e <= deg) {
                int src = node;
                if (e < deg) { int eid = cached ? s_eid[e] : csr_eid[beg+e]; src = esrc[eid]; }
                float t = a_s[(size_t)src*4 + hh] + ad;
                v = t > 0.0f ? t : SLOPE*t;
            }
            #pragma unroll
            for (int msk = 4; msk < 64; msk <<= 1) v = fmaxf(v, __shfl_xor(v, msk, 64));
            m = fmaxf(m, v);
        }
        float den = 0.0f;
        for (int base = 0; base <= deg; base += 16) {
            int e = base + (lane >> 2);
            float v = 0.0f;
            if (e <= deg) {
                int src = node;
                if (e < deg) { int eid = cached ? s_eid[e] : csr_eid[beg+e]; src = esrc[eid]; }
                float t = a_s[(size_t)src*4 + hh] + ad;
                t = t > 0.0f ? t : SLOPE*t;
                v = expf(t - m);
            }
            #pragma unroll
            for (int msk = 4; msk < 64; msk <<= 1) v += __shfl_xor(v, msk, 64);
            den += v;
        }
        if (lane < 4) { s_m[lane] = m; s_den[lane] = den; }
    }
    __syncthreads();

    // Phase 2: weighted aggregation; thread owns cols tid and tid+256
    float acc0 = 0.0f, acc1 = 0.0f;
    int head0 = tid >> 7;        // col tid     -> head 0/1
    int head1 = head0 + 2;       // col tid+256 -> head 2/3
    for (int base = 0; base <= deg; base += 32) {
        int nch = min(32, deg + 1 - base);
        if (tid < 128) {
            int k = tid >> 2, hh2 = tid & 3;
            int e = base + k;
            if (k < nch) {
                int src = node;
                if (e < deg) { int eid = cached ? s_eid[e] : csr_eid[beg+e]; src = esrc[eid]; }
                if (hh2 == 0) s_csrc[k] = src;
                float t = a_s[(size_t)src*4 + hh2] + s_ad[hh2];
                t = t > 0.0f ? t : SLOPE*t;
                s_alpha[k][hh2] = expf(t - s_m[hh2]) / s_den[hh2];
            }
        }
        __syncthreads();
        for (int k = 0; k < nch; ++k) {
            const float* hrow = h + (size_t)s_csrc[k]*HD;
            acc0 = fmaf(s_alpha[k][head0], hrow[tid],       acc0);
            acc1 = fmaf(s_alpha[k][head1], hrow[tid + 256], acc1);
        }
        __syncthreads();
    }
    float v0 = fmaxf(acc0 + bias[tid],       0.0f);
    float v1 = fmaxf(acc1 + bias[tid + 256], 0.0f);
    x1[(size_t)node*HD + tid]       = v0;
    x1[(size_t)node*HD + tid + 256] = v1;
    // topk score: tanh((x1 . w) / ||w||)
    float p = v0*topk_w[tid] + v1*topk_w[tid+256];
    #pragma unroll
    for (int msk = 1; msk < 64; msk <<= 1) p += __shfl_xor(p, msk, 64);
    if ((tid & 63) == 0) s_red[tid >> 6] = p;
    __syncthreads();
    if (tid == 0) {
        float dot = s_red[0] + s_red[1] + s_red[2] + s_red[3];
        scores[node] = tanhf(dot * misc[0]);
    }
}

// ---------------- TopK per graph via exact rank (matches lax.top_k tie-break) ----------------
__global__ __launch_bounds__(256) void topk_kernel(const float* __restrict__ scores,
                                                   int* __restrict__ kept_ids,
                                                   float* __restrict__ kept_vals)
{
    int g = blockIdx.x;
    __shared__ float s[NPG];
    int tid = threadIdx.x;
    for (int i = tid; i < NPG; i += 256) s[i] = scores[g*NPG + i];
    __syncthreads();
    for (int i = tid; i < NPG; i += 256) {
        float si = s[i];
        int rank = 0;
        for (int j = 0; j < NPG; ++j) {
            float sj = s[j];
            rank += (sj > si) || (sj == si && j < i);
        }
        if (rank < KKEEP) {
            kept_ids[g*KKEEP + rank]  = g*NPG + i;
            kept_vals[g*KKEEP + rank] = si;
        }
    }
}

// ---------------- global max + mean pool over kept nodes ----------------
__global__ __launch_bounds__(128) void pool_kernel(const float* __restrict__ x1,
                                                   const int* __restrict__ kept_ids,
                                                   const float* __restrict__ kept_vals,
                                                   float* __restrict__ x2)
{
    int g = blockIdx.x;
    int col = blockIdx.y*128 + threadIdx.x;
    __shared__ int   ids[KKEEP];
    __shared__ float vals[KKEEP];
    for (int i = threadIdx.x; i < KKEEP; i += 128) {
        ids[i]  = kept_ids[g*KKEEP + i];
        vals[i] = kept_vals[g*KKEEP + i];
    }
    __syncthreads();
    float mx = -INFINITY, sm = 0.0f;
    for (int n = 0; n < KKEEP; ++n) {
        float xv = x1[(size_t)ids[n]*HD + col] * vals[n];
        mx = fmaxf(mx, xv);
        sm += xv;
    }
    x2[g*1024 + col]       = mx;
    x2[g*1024 + 512 + col] = sm * (1.0f/KKEEP);
}

// ---------------- MLP head: 1024->128 relu ->64 relu ->8 log_softmax ----------------
__global__ __launch_bounds__(128) void mlp_kernel(const float* __restrict__ x2,
                                                  const float* __restrict__ w1, const float* __restrict__ b1,
                                                  const float* __restrict__ w2, const float* __restrict__ b2,
                                                  const float* __restrict__ w3, const float* __restrict__ b3,
                                                  float* __restrict__ out)
{
    int g = blockIdx.x;
    int tid = threadIdx.x; // 128
    __shared__ float sx[1024];
    __shared__ float sh1[128];
    __shared__ float sh2[64];
    __shared__ float slog[8];
    for (int i = tid; i < 1024; i += 128) sx[i] = x2[g*1024 + i];
    __syncthreads();
    float acc = b1[tid];
    for (int k = 0; k < 1024; ++k) acc = fmaf(sx[k], w1[k*128 + tid], acc);
    sh1[tid] = fmaxf(acc, 0.0f);
    __syncthreads();
    if (tid < 64) {
        float a = b2[tid];
        for (int k = 0; k < 128; ++k) a = fmaf(sh1[k], w2[k*64 + tid], a);
        sh2[tid] = fmaxf(a, 0.0f);
    }
    __syncthreads();
    if (tid < 8) {
        float a = b3[tid];
        for (int k = 0; k < 64; ++k) a = fmaf(sh2[k], w3[k*8 + tid], a);
        slog[tid] = a;
    }
    __syncthreads();
    if (tid == 0) {
        float m = slog[0];
        for (int i = 1; i < 8; ++i) m = fmaxf(m, slog[i]);
        float ssum = 0.0f;
        for (int i = 0; i < 8; ++i) ssum += expf(slog[i] - m);
        float lse = m + logf(ssum);
        for (int i = 0; i < 8; ++i) out[g*8 + i] = slog[i] - lse;
    }
}

extern "C" void kernel_launch(void* const* d_in, const int* in_sizes, int n_in,
                              void* d_out, int out_size, void* d_ws, size_t ws_size,
                              hipStream_t stream) {
    const float* x        = (const float*)d_in[0];
    const int*   ei       = (const int*)d_in[1];     // [2, E] int32
    // d_in[2] batch, d_in[3] edge_attr: unused
    const float* W        = (const float*)d_in[4];
    const float* att_src  = (const float*)d_in[5];
    const float* att_dst  = (const float*)d_in[6];
    const float* bias     = (const float*)d_in[7];
    const float* topk_w   = (const float*)d_in[8];
    const float* w1       = (const float*)d_in[9];
    const float* b1       = (const float*)d_in[10];
    const float* w2       = (const float*)d_in[11];
    const float* b2       = (const float*)d_in[12];
    const float* w3       = (const float*)d_in[13];
    const float* b3       = (const float*)d_in[14];
    float* out = (float*)d_out;

    const int* src = ei;
    const int* dst = ei + E_EDGES;

    char* wsb = (char*)d_ws;
    size_t off = 0;
    auto alloc = [&](size_t bytes) -> void* {
        void* p = (void*)(wsb + off);
        off += (bytes + 255) & ~(size_t)255;
        return p;
    };
    float* h        = (float*)alloc((size_t)N_NODES*HD*4);
    float* x1       = (float*)alloc((size_t)N_NODES*HD*4);
    float* a_s      = (float*)alloc((size_t)N_NODES*4*4);
    float* a_d      = (float*)alloc((size_t)N_NODES*4*4);
    float* Ws       = (float*)alloc(F_IN*4*4);
    float* Wd       = (float*)alloc(F_IN*4*4);
    float* misc     = (float*)alloc(256);
    int*   counts   = (int*)alloc((size_t)N_NODES*4);
    int*   offsets  = (int*)alloc((size_t)(N_NODES+1)*4);
    int*   cursor   = (int*)alloc((size_t)N_NODES*4);
    int*   csr_eid  = (int*)alloc((size_t)E_EDGES*4);
    float* scores   = (float*)alloc((size_t)N_NODES*4);
    int*   kept_ids = (int*)alloc((size_t)B_GRAPHS*KKEEP*4);
    float* kept_vals= (float*)alloc((size_t)B_GRAPHS*KKEEP*4);
    float* x2       = (float*)alloc((size_t)B_GRAPHS*1024*4);

    hipMemsetAsync(counts, 0, (size_t)N_NODES*4, stream);
    prep_kernel<<<1, 256, 0, stream>>>(W, att_src, att_dst, topk_w, Ws, Wd, misc);
    compute_h_kernel<<<N_NODES/NPB, 256, 0, stream>>>(x, W, Ws, Wd, h, a_s, a_d);
    hist_kernel<<<640, 256, 0, stream>>>(dst, counts);
    scan_kernel<<<1, 1024, 0, stream>>>(counts, offsets, cursor);
    fill_kernel<<<640, 256, 0, stream>>>(dst, cursor, csr_eid);
    gat_agg_kernel<<<N_NODES, 256, 0, stream>>>(h, a_s, a_d, offsets, csr_eid, src,
                                                bias, topk_w, misc, x1, scores);
    topk_kernel<<<B_GRAPHS, 256, 0, stream>>>(scores, kept_ids, kept_vals);
    pool_kernel<<<dim3(B_GRAPHS, 4), 128, 0, stream>>>(x1, kept_ids, kept_vals, x2);
    mlp_kernel<<<B_GRAPHS, 128, 0, stream>>>(x2, w1, b1, w2, b2, w3, b3, out);
}

// Round 2
// 207.124 us; speedup vs baseline: 2.1631x; 2.1631x over previous
//
#include <hip/hip_runtime.h>
#include <math.h>

// Net_Without_GINEgPool: GATConv(32,128,h=4) + TopKPooling(0.8) + max/mean pool + MLP head.
// R2: wave-per-node GAT (float4 gathers, XCD swizzle, in-register softmax, ds_permute sort),
//     slot-table CSR (no scan), register-W compute_h, split topk/pool, fused pool-finalize+MLP.

#define N_NODES 32000
#define B_GRAPHS 32
#define NPG 1000
#define DEGC 10
#define E_EDGES (N_NODES*DEGC)
#define HD 512
#define F_IN 32
#define KKEEP 800
#define SLOPE 0.2f
#define CAP 64

// ---------------- prep: Ws/Wd = W folded with att vectors; inv-norm of topk_w ----------------
__global__ void prep_kernel(const float* __restrict__ W, const float* __restrict__ att_src,
                            const float* __restrict__ att_dst, const float* __restrict__ topk_w,
                            float* __restrict__ Ws, float* __restrict__ Wd, float* __restrict__ misc)
{
    int tid = threadIdx.x; // 256
    if (tid < 128) {
        int f = tid >> 2, hh = tid & 3;
        float s1 = 0.f, s2 = 0.f;
        for (int d = 0; d < 128; ++d) {
            float w = W[f*HD + hh*128 + d];
            s1 = fmaf(w, att_src[hh*128 + d], s1);
            s2 = fmaf(w, att_dst[hh*128 + d], s2);
        }
        Ws[f*4+hh] = s1;
        Wd[f*4+hh] = s2;
    }
    __shared__ float red[256];
    float tw0 = topk_w[tid], tw1 = topk_w[tid+256];
    red[tid] = tw0*tw0 + tw1*tw1;
    __syncthreads();
    for (int s = 128; s > 0; s >>= 1) { if (tid < s) red[tid] += red[tid+s]; __syncthreads(); }
    if (tid == 0) misc[0] = 1.0f / sqrtf(red[0]);
}

// ---------------- h = x @ W  [N,512]; a_s = x @ Ws, a_d = x @ Wd  [N,4] ----------------
#define NPB 32
__global__ __launch_bounds__(256) void compute_h_kernel(
    const float* __restrict__ x, const float* __restrict__ W,
    const float* __restrict__ Ws, const float* __restrict__ Wd,
    float* __restrict__ h, float* __restrict__ a_s, float* __restrict__ a_d)
{
    __shared__ float s_x[NPB*F_IN];   // 4 KB
    int tid = threadIdx.x;            // 256
    int n0 = blockIdx.x * NPB;
    // W columns tid and tid+256 held in registers (64 VGPRs)
    float wc0[F_IN], wc1[F_IN];
    #pragma unroll
    for (int f = 0; f < F_IN; ++f) {
        wc0[f] = W[f*HD + tid];
        wc1[f] = W[f*HD + tid + 256];
    }
    const float4* xg = (const float4*)(x + (size_t)n0*F_IN);
    float4* sx4 = (float4*)s_x;
    for (int i = tid; i < NPB*F_IN/4; i += 256) sx4[i] = xg[i];
    __syncthreads();
    for (int n = 0; n < NPB; ++n) {
        const float4* xr = (const float4*)(s_x + n*F_IN);
        float acc0 = 0.f, acc1 = 0.f;
        #pragma unroll
        for (int f4 = 0; f4 < F_IN/4; ++f4) {
            float4 xv = xr[f4];
            acc0 = fmaf(xv.x, wc0[f4*4+0], acc0); acc1 = fmaf(xv.x, wc1[f4*4+0], acc1);
            acc0 = fmaf(xv.y, wc0[f4*4+1], acc0); acc1 = fmaf(xv.y, wc1[f4*4+1], acc1);
            acc0 = fmaf(xv.z, wc0[f4*4+2], acc0); acc1 = fmaf(xv.z, wc1[f4*4+2], acc1);
            acc0 = fmaf(xv.w, wc0[f4*4+3], acc0); acc1 = fmaf(xv.w, wc1[f4*4+3], acc1);
        }
        h[(size_t)(n0+n)*HD + tid]       = acc0;
        h[(size_t)(n0+n)*HD + tid + 256] = acc1;
    }
    // a_s/a_d: tid = n*8 + hh*2 + which
    {
        int n = tid >> 3, hh = (tid >> 1) & 3, which = tid & 1;
        const float* Wx = which ? Wd : Ws;
        const float* xr = s_x + n*F_IN;
        float s = 0.f;
        #pragma unroll
        for (int f = 0; f < F_IN; ++f) s = fmaf(xr[f], Wx[f*4+hh], s);
        float* dp = which ? a_d : a_s;
        dp[(size_t)(n0+n)*4 + hh] = s;
    }
}

// ---------------- slot-table CSR: counts + fixed-capacity edge lists ----------------
__global__ void build_slots_kernel(const int* __restrict__ dst, int* __restrict__ counts,
                                   int* __restrict__ slots)
{
    int i = blockIdx.x*blockDim.x + threadIdx.x;
    int stride = gridDim.x*blockDim.x;
    for (; i < E_EDGES; i += stride) {
        int d = dst[i];
        int p = atomicAdd(&counts[d], 1);
        if (p < CAP) slots[d*CAP + p] = i;
    }
}

// ---------------- wave-per-node GAT: softmax in registers + float4 aggregation ----------------
__global__ __launch_bounds__(256) void gat_agg_kernel(
    const float* __restrict__ h, const float* __restrict__ a_s, const float* __restrict__ a_d,
    const int* __restrict__ counts, const int* __restrict__ slots, const int* __restrict__ esrc,
    const float* __restrict__ bias, const float* __restrict__ topk_w, const float* __restrict__ misc,
    float* __restrict__ x1, float* __restrict__ scores)
{
    __shared__ int    s_src[4][CAP];
    __shared__ float4 s_al[4][CAP];
    int tid = threadIdx.x;
    int wid = tid >> 6, lane = tid & 63;
    // XCD swizzle: XCD k handles nodes [k*4000,(k+1)*4000) -> per-XCD L2 holds 4 graphs' h slice
    int grp  = (blockIdx.x & 7) * 1000 + (blockIdx.x >> 3);
    int node = grp*4 + wid;
    int deg  = min(counts[node], CAP);

    // --- deterministic edge order: rank-sort eids within the wave ---
    int key = (lane < deg) ? slots[node*CAP + lane] : (0x7FFF0000 + lane);
    int rank = 0;
    for (int j = 0; j < deg; ++j) rank += (__shfl(key, j, 64) < key);
    if (lane >= deg) rank = lane;
    int sorted_eid = __builtin_amdgcn_ds_permute(rank << 2, key);  // lane r holds r-th smallest

    int src = node;
    if (lane < deg) src = esrc[sorted_eid];

    // --- attention logits (lane = edge, 4 heads in registers) ---
    float4 ad    = *(const float4*)(a_d + (size_t)node*4);
    float4 aself = *(const float4*)(a_s + (size_t)node*4);
    float4 asrc  = make_float4(0.f,0.f,0.f,0.f);
    if (lane < deg) asrc = *(const float4*)(a_s + (size_t)src*4);

    float t[4], ts[4];
    {
        float u;
        u = asrc.x + ad.x; t[0] = u > 0.f ? u : SLOPE*u;
        u = asrc.y + ad.y; t[1] = u > 0.f ? u : SLOPE*u;
        u = asrc.z + ad.z; t[2] = u > 0.f ? u : SLOPE*u;
        u = asrc.w + ad.w; t[3] = u > 0.f ? u : SLOPE*u;
        u = aself.x + ad.x; ts[0] = u > 0.f ? u : SLOPE*u;
        u = aself.y + ad.y; ts[1] = u > 0.f ? u : SLOPE*u;
        u = aself.z + ad.z; ts[2] = u > 0.f ? u : SLOPE*u;
        u = aself.w + ad.w; ts[3] = u > 0.f ? u : SLOPE*u;
    }
    #pragma unroll
    for (int hh = 0; hh < 4; ++hh) if (lane >= deg) t[hh] = -INFINITY;

    float al[4], alself[4];
    #pragma unroll
    for (int hh = 0; hh < 4; ++hh) {
        float m = t[hh];
        #pragma unroll
        for (int msk = 1; msk < 64; msk <<= 1) m = fmaxf(m, __shfl_xor(m, msk, 64));
        m = fmaxf(m, ts[hh]);
        float ex  = (lane < deg) ? expf(t[hh] - m) : 0.f;
        float exs = expf(ts[hh] - m);
        float den = ex;
        #pragma unroll
        for (int msk = 1; msk < 64; msk <<= 1) den += __shfl_xor(den, msk, 64);
        den += exs;
        al[hh]     = ex / den;
        alself[hh] = exs / den;
    }
    if (lane < deg) {
        s_src[wid][lane] = src;
        s_al[wid][lane]  = make_float4(al[0], al[1], al[2], al[3]);
    }
    __syncthreads();

    // --- aggregation: lane owns cols [lane*4, +4) and [256+lane*4, +4) ---
    int c0 = lane*4, c1 = 256 + lane*4;
    bool hi = lane >= 32;                      // head of c0 = hi?1:0, head of c1 = hi?3:2
    float4 acc0 = make_float4(0.f,0.f,0.f,0.f);
    float4 acc1 = make_float4(0.f,0.f,0.f,0.f);
    #define EDGE_STEP(E_IDX)                                                          \
        {   int se = s_src[wid][E_IDX];                                               \
            float4 a4 = s_al[wid][E_IDX];                                             \
            float a0 = hi ? a4.y : a4.x;                                              \
            float a1 = hi ? a4.w : a4.z;                                              \
            float4 v0 = *(const float4*)(h + (size_t)se*HD + c0);                     \
            float4 v1 = *(const float4*)(h + (size_t)se*HD + c1);                     \
            acc0.x = fmaf(a0, v0.x, acc0.x); acc0.y = fmaf(a0, v0.y, acc0.y);         \
            acc0.z = fmaf(a0, v0.z, acc0.z); acc0.w = fmaf(a0, v0.w, acc0.w);         \
            acc1.x = fmaf(a1, v1.x, acc1.x); acc1.y = fmaf(a1, v1.y, acc1.y);         \
            acc1.z = fmaf(a1, v1.z, acc1.z); acc1.w = fmaf(a1, v1.w, acc1.w); }
    int e = 0;
    for (; e + 2 <= deg; e += 2) { EDGE_STEP(e); EDGE_STEP(e+1); }
    if (e < deg) EDGE_STEP(e);
    // self-loop last (matches reference concat order)
    {
        float a0 = hi ? alself[1] : alself[0];
        float a1 = hi ? alself[3] : alself[2];
        float4 v0 = *(const float4*)(h + (size_t)node*HD + c0);
        float4 v1 = *(const float4*)(h + (size_t)node*HD + c1);
        acc0.x = fmaf(a0, v0.x, acc0.x); acc0.y = fmaf(a0, v0.y, acc0.y);
        acc0.z = fmaf(a0, v0.z, acc0.z); acc0.w = fmaf(a0, v0.w, acc0.w);
        acc1.x = fmaf(a1, v1.x, acc1.x); acc1.y = fmaf(a1, v1.y, acc1.y);
        acc1.z = fmaf(a1, v1.z, acc1.z); acc1.w = fmaf(a1, v1.w, acc1.w);
    }
    #undef EDGE_STEP

    float4 b0 = *(const float4*)(bias + c0);
    float4 b1 = *(const float4*)(bias + c1);
    float4 v0, v1;
    v0.x = fmaxf(acc0.x + b0.x, 0.f); v0.y = fmaxf(acc0.y + b0.y, 0.f);
    v0.z = fmaxf(acc0.z + b0.z, 0.f); v0.w = fmaxf(acc0.w + b0.w, 0.f);
    v1.x = fmaxf(acc1.x + b1.x, 0.f); v1.y = fmaxf(acc1.y + b1.y, 0.f);
    v1.z = fmaxf(acc1.z + b1.z, 0.f); v1.w = fmaxf(acc1.w + b1.w, 0.f);
    *(float4*)(x1 + (size_t)node*HD + c0) = v0;
    *(float4*)(x1 + (size_t)node*HD + c1) = v1;

    float4 tw0 = *(const float4*)(topk_w + c0);
    float4 tw1 = *(const float4*)(topk_w + c1);
    float p = v0.x*tw0.x + v0.y*tw0.y + v0.z*tw0.z + v0.w*tw0.w
            + v1.x*tw1.x + v1.y*tw1.y + v1.z*tw1.z + v1.w*tw1.w;
    #pragma unroll
    for (int msk = 1; msk < 64; msk <<= 1) p += __shfl_xor(p, msk, 64);
    if (lane == 0) scores[node] = tanhf(p * misc[0]);
}

// ---------------- TopK per graph via exact rank; 4 blocks/graph ----------------
__global__ __launch_bounds__(256) void topk_kernel(const float* __restrict__ scores,
                                                   int* __restrict__ kept_ids,
                                                   float* __restrict__ kept_vals)
{
    int g = blockIdx.x, part = blockIdx.y;
    __shared__ float s[NPG];
    int tid = threadIdx.x;
    for (int i = tid; i < NPG; i += 256) s[i] = scores[g*NPG + i];
    __syncthreads();
    int i = part*250 + tid;
    if (tid < 250) {
        float si = s[i];
        int rank = 0;
        for (int j = 0; j < NPG; ++j) {
            float sj = s[j];
            rank += (sj > si) || (sj == si && j < i);
        }
        if (rank < KKEEP) {
            kept_ids[g*KKEEP + rank]  = g*NPG + i;
            kept_vals[g*KKEEP + rank] = si;
        }
    }
}

// ---------------- pool partials: 8 row-chunks per graph, float4 cols ----------------
#define RCHUNK 100
__global__ __launch_bounds__(128) void pool_partial_kernel(
    const float* __restrict__ x1, const int* __restrict__ kept_ids,
    const float* __restrict__ kept_vals, float* __restrict__ pmax, float* __restrict__ psum)
{
    int g = blockIdx.x, c = blockIdx.y;
    int tid = threadIdx.x;   // 128, float4 col = tid*4
    __shared__ int   ids[RCHUNK];
    __shared__ float vals[RCHUNK];
    for (int i = tid; i < RCHUNK; i += 128) {
        ids[i]  = kept_ids[g*KKEEP + c*RCHUNK + i];
        vals[i] = kept_vals[g*KKEEP + c*RCHUNK + i];
    }
    __syncthreads();
    float4 mx = make_float4(-INFINITY,-INFINITY,-INFINITY,-INFINITY);
    float4 sm = make_float4(0.f,0.f,0.f,0.f);
    for (int r = 0; r < RCHUNK; ++r) {
        float4 v = *(const float4*)(x1 + (size_t)ids[r]*HD + tid*4);
        float vl = vals[r];
        v.x *= vl; v.y *= vl; v.z *= vl; v.w *= vl;
        mx.x = fmaxf(mx.x, v.x); mx.y = fmaxf(mx.y, v.y);
        mx.z = fmaxf(mx.z, v.z); mx.w = fmaxf(mx.w, v.w);
        sm.x += v.x; sm.y += v.y; sm.z += v.z; sm.w += v.w;
    }
    *(float4*)(pmax + (size_t)(g*8 + c)*HD + tid*4) = mx;
    *(float4*)(psum + (size_t)(g*8 + c)*HD + tid*4) = sm;
}

// ---------------- finalize pool + MLP head ----------------
__global__ __launch_bounds__(128) void mlp_kernel(
    const float* __restrict__ pmax, const float* __restrict__ psum,
    const float* __restrict__ w1, const float* __restrict__ b1,
    const float* __restrict__ w2, const float* __restrict__ b2,
    const float* __restrict__ w3, const float* __restrict__ b3,
    float* __restrict__ out)
{
    int g = blockIdx.x;
    int tid = threadIdx.x; // 128
    __shared__ float sx[1024];
    __shared__ float sh1[128];
    __shared__ float sh2[64];
    __shared__ float slog[8];
    {
        float4 mx = *(const float4*)(pmax + (size_t)(g*8)*HD + tid*4);
        float4 sm = *(const float4*)(psum + (size_t)(g*8)*HD + tid*4);
        for (int c = 1; c < 8; ++c) {
            float4 m2 = *(const float4*)(pmax + (size_t)(g*8 + c)*HD + tid*4);
            float4 s2 = *(const float4*)(psum + (size_t)(g*8 + c)*HD + tid*4);
            mx.x = fmaxf(mx.x, m2.x); mx.y = fmaxf(mx.y, m2.y);
            mx.z = fmaxf(mx.z, m2.z); mx.w = fmaxf(mx.w, m2.w);
            sm.x += s2.x; sm.y += s2.y; sm.z += s2.z; sm.w += s2.w;
        }
        sx[tid*4+0] = mx.x; sx[tid*4+1] = mx.y; sx[tid*4+2] = mx.z; sx[tid*4+3] = mx.w;
        const float inv = 1.0f/KKEEP;
        sx[512+tid*4+0] = sm.x*inv; sx[512+tid*4+1] = sm.y*inv;
        sx[512+tid*4+2] = sm.z*inv; sx[512+tid*4+3] = sm.w*inv;
    }
    __syncthreads();
    float acc = b1[tid];
    #pragma unroll 4
    for (int k = 0; k < 1024; ++k) acc = fmaf(sx[k], w1[k*128 + tid], acc);
    sh1[tid] = fmaxf(acc, 0.0f);
    __syncthreads();
    if (tid < 64) {
        float a = b2[tid];
        for (int k = 0; k < 128; ++k) a = fmaf(sh1[k], w2[k*64 + tid], a);
        sh2[tid] = fmaxf(a, 0.0f);
    }
    __syncthreads();
    if (tid < 8) {
        float a = b3[tid];
        for (int k = 0; k < 64; ++k) a = fmaf(sh2[k], w3[k*8 + tid], a);
        slog[tid] = a;
    }
    __syncthreads();
    if (tid == 0) {
        float m = slog[0];
        for (int i = 1; i < 8; ++i) m = fmaxf(m, slog[i]);
        float ssum = 0.0f;
        for (int i = 0; i < 8; ++i) ssum += expf(slog[i] - m);
        float lse = m + logf(ssum);
        for (int i = 0; i < 8; ++i) out[g*8 + i] = slog[i] - lse;
    }
}

extern "C" void kernel_launch(void* const* d_in, const int* in_sizes, int n_in,
                              void* d_out, int out_size, void* d_ws, size_t ws_size,
                              hipStream_t stream) {
    const float* x        = (const float*)d_in[0];
    const int*   ei       = (const int*)d_in[1];
    const float* W        = (const float*)d_in[4];
    const float* att_src  = (const float*)d_in[5];
    const float* att_dst  = (const float*)d_in[6];
    const float* bias     = (const float*)d_in[7];
    const float* topk_w   = (const float*)d_in[8];
    const float* w1       = (const float*)d_in[9];
    const float* b1       = (const float*)d_in[10];
    const float* w2       = (const float*)d_in[11];
    const float* b2       = (const float*)d_in[12];
    const float* w3       = (const float*)d_in[13];
    const float* b3       = (const float*)d_in[14];
    float* out = (float*)d_out;

    const int* src = ei;
    const int* dst = ei + E_EDGES;

    char* wsb = (char*)d_ws;
    size_t off = 0;
    auto alloc = [&](size_t bytes) -> void* {
        void* p = (void*)(wsb + off);
        off += (bytes + 255) & ~(size_t)255;
        return p;
    };
    float* h        = (float*)alloc((size_t)N_NODES*HD*4);
    float* x1       = (float*)alloc((size_t)N_NODES*HD*4);
    float* a_s      = (float*)alloc((size_t)N_NODES*4*4);
    float* a_d      = (float*)alloc((size_t)N_NODES*4*4);
    float* Ws       = (float*)alloc(F_IN*4*4);
    float* Wd       = (float*)alloc(F_IN*4*4);
    float* misc     = (float*)alloc(256);
    int*   counts   = (int*)alloc((size_t)N_NODES*4);
    int*   slots    = (int*)alloc((size_t)N_NODES*CAP*4);
    float* scores   = (float*)alloc((size_t)N_NODES*4);
    int*   kept_ids = (int*)alloc((size_t)B_GRAPHS*KKEEP*4);
    float* kept_vals= (float*)alloc((size_t)B_GRAPHS*KKEEP*4);
    float* pmax     = (float*)alloc((size_t)B_GRAPHS*8*HD*4);
    float* psum     = (float*)alloc((size_t)B_GRAPHS*8*HD*4);

    hipMemsetAsync(counts, 0, (size_t)N_NODES*4, stream);
    prep_kernel<<<1, 256, 0, stream>>>(W, att_src, att_dst, topk_w, Ws, Wd, misc);
    compute_h_kernel<<<N_NODES/NPB, 256, 0, stream>>>(x, W, Ws, Wd, h, a_s, a_d);
    build_slots_kernel<<<640, 256, 0, stream>>>(dst, counts, slots);
    gat_agg_kernel<<<N_NODES/4, 256, 0, stream>>>(h, a_s, a_d, counts, slots, src,
                                                  bias, topk_w, misc, x1, scores);
    topk_kernel<<<dim3(B_GRAPHS, 4), 256, 0, stream>>>(scores, kept_ids, kept_vals);
    pool_partial_kernel<<<dim3(B_GRAPHS, 8), 128, 0, stream>>>(x1, kept_ids, kept_vals, pmax, psum);
    mlp_kernel<<<B_GRAPHS, 128, 0, stream>>>(pmax, psum, w1, b1, w2, b2, w3, b3, out);
}

// Round 3
// 151.188 us; speedup vs baseline: 2.9634x; 1.3700x over previous
//
#include <hip/hip_runtime.h>
#include <math.h>

// Net_Without_GINEgPool: GATConv(32,128,h=4) + TopKPooling(0.8) + max/mean pool + MLP head.
// R3: k-split MLP (the 110us latency-bound layer-1 loop -> 8-way k-parallel float4 loads).
//     Rest unchanged from R2 (wave-per-node GAT, slot-table CSR, register-W compute_h).

#define N_NODES 32000
#define B_GRAPHS 32
#define NPG 1000
#define DEGC 10
#define E_EDGES (N_NODES*DEGC)
#define HD 512
#define F_IN 32
#define KKEEP 800
#define SLOPE 0.2f
#define CAP 64

// ---------------- prep: Ws/Wd = W folded with att vectors; inv-norm of topk_w ----------------
__global__ void prep_kernel(const float* __restrict__ W, const float* __restrict__ att_src,
                            const float* __restrict__ att_dst, const float* __restrict__ topk_w,
                            float* __restrict__ Ws, float* __restrict__ Wd, float* __restrict__ misc)
{
    int tid = threadIdx.x; // 256
    if (tid < 128) {
        int f = tid >> 2, hh = tid & 3;
        float s1 = 0.f, s2 = 0.f;
        for (int d = 0; d < 128; ++d) {
            float w = W[f*HD + hh*128 + d];
            s1 = fmaf(w, att_src[hh*128 + d], s1);
            s2 = fmaf(w, att_dst[hh*128 + d], s2);
        }
        Ws[f*4+hh] = s1;
        Wd[f*4+hh] = s2;
    }
    __shared__ float red[256];
    float tw0 = topk_w[tid], tw1 = topk_w[tid+256];
    red[tid] = tw0*tw0 + tw1*tw1;
    __syncthreads();
    for (int s = 128; s > 0; s >>= 1) { if (tid < s) red[tid] += red[tid+s]; __syncthreads(); }
    if (tid == 0) misc[0] = 1.0f / sqrtf(red[0]);
}

// ---------------- h = x @ W  [N,512]; a_s = x @ Ws, a_d = x @ Wd  [N,4] ----------------
#define NPB 32
__global__ __launch_bounds__(256) void compute_h_kernel(
    const float* __restrict__ x, const float* __restrict__ W,
    const float* __restrict__ Ws, const float* __restrict__ Wd,
    float* __restrict__ h, float* __restrict__ a_s, float* __restrict__ a_d)
{
    __shared__ float s_x[NPB*F_IN];   // 4 KB
    int tid = threadIdx.x;            // 256
    int n0 = blockIdx.x * NPB;
    float wc0[F_IN], wc1[F_IN];
    #pragma unroll
    for (int f = 0; f < F_IN; ++f) {
        wc0[f] = W[f*HD + tid];
        wc1[f] = W[f*HD + tid + 256];
    }
    const float4* xg = (const float4*)(x + (size_t)n0*F_IN);
    float4* sx4 = (float4*)s_x;
    for (int i = tid; i < NPB*F_IN/4; i += 256) sx4[i] = xg[i];
    __syncthreads();
    for (int n = 0; n < NPB; ++n) {
        const float4* xr = (const float4*)(s_x + n*F_IN);
        float acc0 = 0.f, acc1 = 0.f;
        #pragma unroll
        for (int f4 = 0; f4 < F_IN/4; ++f4) {
            float4 xv = xr[f4];
            acc0 = fmaf(xv.x, wc0[f4*4+0], acc0); acc1 = fmaf(xv.x, wc1[f4*4+0], acc1);
            acc0 = fmaf(xv.y, wc0[f4*4+1], acc0); acc1 = fmaf(xv.y, wc1[f4*4+1], acc1);
            acc0 = fmaf(xv.z, wc0[f4*4+2], acc0); acc1 = fmaf(xv.z, wc1[f4*4+2], acc1);
            acc0 = fmaf(xv.w, wc0[f4*4+3], acc0); acc1 = fmaf(xv.w, wc1[f4*4+3], acc1);
        }
        h[(size_t)(n0+n)*HD + tid]       = acc0;
        h[(size_t)(n0+n)*HD + tid + 256] = acc1;
    }
    {
        int n = tid >> 3, hh = (tid >> 1) & 3, which = tid & 1;
        const float* Wx = which ? Wd : Ws;
        const float* xr = s_x + n*F_IN;
        float s = 0.f;
        #pragma unroll
        for (int f = 0; f < F_IN; ++f) s = fmaf(xr[f], Wx[f*4+hh], s);
        float* dp = which ? a_d : a_s;
        dp[(size_t)(n0+n)*4 + hh] = s;
    }
}

// ---------------- slot-table CSR: counts + fixed-capacity edge lists ----------------
__global__ void build_slots_kernel(const int* __restrict__ dst, int* __restrict__ counts,
                                   int* __restrict__ slots)
{
    int i = blockIdx.x*blockDim.x + threadIdx.x;
    int stride = gridDim.x*blockDim.x;
    for (; i < E_EDGES; i += stride) {
        int d = dst[i];
        int p = atomicAdd(&counts[d], 1);
        if (p < CAP) slots[d*CAP + p] = i;
    }
}

// ---------------- wave-per-node GAT: softmax in registers + float4 aggregation ----------------
__global__ __launch_bounds__(256) void gat_agg_kernel(
    const float* __restrict__ h, const float* __restrict__ a_s, const float* __restrict__ a_d,
    const int* __restrict__ counts, const int* __restrict__ slots, const int* __restrict__ esrc,
    const float* __restrict__ bias, const float* __restrict__ topk_w, const float* __restrict__ misc,
    float* __restrict__ x1, float* __restrict__ scores)
{
    __shared__ int    s_src[4][CAP];
    __shared__ float4 s_al[4][CAP];
    int tid = threadIdx.x;
    int wid = tid >> 6, lane = tid & 63;
    int grp  = (blockIdx.x & 7) * 1000 + (blockIdx.x >> 3);
    int node = grp*4 + wid;
    int deg  = min(counts[node], CAP);

    int key = (lane < deg) ? slots[node*CAP + lane] : (0x7FFF0000 + lane);
    int rank = 0;
    for (int j = 0; j < deg; ++j) rank += (__shfl(key, j, 64) < key);
    if (lane >= deg) rank = lane;
    int sorted_eid = __builtin_amdgcn_ds_permute(rank << 2, key);

    int src = node;
    if (lane < deg) src = esrc[sorted_eid];

    float4 ad    = *(const float4*)(a_d + (size_t)node*4);
    float4 aself = *(const float4*)(a_s + (size_t)node*4);
    float4 asrc  = make_float4(0.f,0.f,0.f,0.f);
    if (lane < deg) asrc = *(const float4*)(a_s + (size_t)src*4);

    float t[4], ts[4];
    {
        float u;
        u = asrc.x + ad.x; t[0] = u > 0.f ? u : SLOPE*u;
        u = asrc.y + ad.y; t[1] = u > 0.f ? u : SLOPE*u;
        u = asrc.z + ad.z; t[2] = u > 0.f ? u : SLOPE*u;
        u = asrc.w + ad.w; t[3] = u > 0.f ? u : SLOPE*u;
        u = aself.x + ad.x; ts[0] = u > 0.f ? u : SLOPE*u;
        u = aself.y + ad.y; ts[1] = u > 0.f ? u : SLOPE*u;
        u = aself.z + ad.z; ts[2] = u > 0.f ? u : SLOPE*u;
        u = aself.w + ad.w; ts[3] = u > 0.f ? u : SLOPE*u;
    }
    #pragma unroll
    for (int hh = 0; hh < 4; ++hh) if (lane >= deg) t[hh] = -INFINITY;

    float al[4], alself[4];
    #pragma unroll
    for (int hh = 0; hh < 4; ++hh) {
        float m = t[hh];
        #pragma unroll
        for (int msk = 1; msk < 64; msk <<= 1) m = fmaxf(m, __shfl_xor(m, msk, 64));
        m = fmaxf(m, ts[hh]);
        float ex  = (lane < deg) ? expf(t[hh] - m) : 0.f;
        float exs = expf(ts[hh] - m);
        float den = ex;
        #pragma unroll
        for (int msk = 1; msk < 64; msk <<= 1) den += __shfl_xor(den, msk, 64);
        den += exs;
        al[hh]     = ex / den;
        alself[hh] = exs / den;
    }
    if (lane < deg) {
        s_src[wid][lane] = src;
        s_al[wid][lane]  = make_float4(al[0], al[1], al[2], al[3]);
    }
    __syncthreads();

    int c0 = lane*4, c1 = 256 + lane*4;
    bool hi = lane >= 32;
    float4 acc0 = make_float4(0.f,0.f,0.f,0.f);
    float4 acc1 = make_float4(0.f,0.f,0.f,0.f);
    #define EDGE_STEP(E_IDX)                                                          \
        {   int se = s_src[wid][E_IDX];                                               \
            float4 a4 = s_al[wid][E_IDX];                                             \
            float a0 = hi ? a4.y : a4.x;                                              \
            float a1 = hi ? a4.w : a4.z;                                              \
            float4 v0 = *(const float4*)(h + (size_t)se*HD + c0);                     \
            float4 v1 = *(const float4*)(h + (size_t)se*HD + c1);                     \
            acc0.x = fmaf(a0, v0.x, acc0.x); acc0.y = fmaf(a0, v0.y, acc0.y);         \
            acc0.z = fmaf(a0, v0.z, acc0.z); acc0.w = fmaf(a0, v0.w, acc0.w);         \
            acc1.x = fmaf(a1, v1.x, acc1.x); acc1.y = fmaf(a1, v1.y, acc1.y);         \
            acc1.z = fmaf(a1, v1.z, acc1.z); acc1.w = fmaf(a1, v1.w, acc1.w); }
    int e = 0;
    for (; e + 2 <= deg; e += 2) { EDGE_STEP(e); EDGE_STEP(e+1); }
    if (e < deg) EDGE_STEP(e);
    {
        float a0 = hi ? alself[1] : alself[0];
        float a1 = hi ? alself[3] : alself[2];
        float4 v0 = *(const float4*)(h + (size_t)node*HD + c0);
        float4 v1 = *(const float4*)(h + (size_t)node*HD + c1);
        acc0.x = fmaf(a0, v0.x, acc0.x); acc0.y = fmaf(a0, v0.y, acc0.y);
        acc0.z = fmaf(a0, v0.z, acc0.z); acc0.w = fmaf(a0, v0.w, acc0.w);
        acc1.x = fmaf(a1, v1.x, acc1.x); acc1.y = fmaf(a1, v1.y, acc1.y);
        acc1.z = fmaf(a1, v1.z, acc1.z); acc1.w = fmaf(a1, v1.w, acc1.w);
    }
    #undef EDGE_STEP

    float4 b0 = *(const float4*)(bias + c0);
    float4 b1 = *(const float4*)(bias + c1);
    float4 v0, v1;
    v0.x = fmaxf(acc0.x + b0.x, 0.f); v0.y = fmaxf(acc0.y + b0.y, 0.f);
    v0.z = fmaxf(acc0.z + b0.z, 0.f); v0.w = fmaxf(acc0.w + b0.w, 0.f);
    v1.x = fmaxf(acc1.x + b1.x, 0.f); v1.y = fmaxf(acc1.y + b1.y, 0.f);
    v1.z = fmaxf(acc1.z + b1.z, 0.f); v1.w = fmaxf(acc1.w + b1.w, 0.f);
    *(float4*)(x1 + (size_t)node*HD + c0) = v0;
    *(float4*)(x1 + (size_t)node*HD + c1) = v1;

    float4 tw0 = *(const float4*)(topk_w + c0);
    float4 tw1 = *(const float4*)(topk_w + c1);
    float p = v0.x*tw0.x + v0.y*tw0.y + v0.z*tw0.z + v0.w*tw0.w
            + v1.x*tw1.x + v1.y*tw1.y + v1.z*tw1.z + v1.w*tw1.w;
    #pragma unroll
    for (int msk = 1; msk < 64; msk <<= 1) p += __shfl_xor(p, msk, 64);
    if (lane == 0) scores[node] = tanhf(p * misc[0]);
}

// ---------------- TopK per graph via exact rank; 4 blocks/graph ----------------
__global__ __launch_bounds__(256) void topk_kernel(const float* __restrict__ scores,
                                                   int* __restrict__ kept_ids,
                                                   float* __restrict__ kept_vals)
{
    int g = blockIdx.x, part = blockIdx.y;
    __shared__ float s[NPG];
    int tid = threadIdx.x;
    for (int i = tid; i < NPG; i += 256) s[i] = scores[g*NPG + i];
    __syncthreads();
    int i = part*250 + tid;
    if (tid < 250) {
        float si = s[i];
        int rank = 0;
        for (int j = 0; j < NPG; ++j) {
            float sj = s[j];
            rank += (sj > si) || (sj == si && j < i);
        }
        if (rank < KKEEP) {
            kept_ids[g*KKEEP + rank]  = g*NPG + i;
            kept_vals[g*KKEEP + rank] = si;
        }
    }
}

// ---------------- pool partials: 8 row-chunks per graph, float4 cols ----------------
#define RCHUNK 100
__global__ __launch_bounds__(128) void pool_partial_kernel(
    const float* __restrict__ x1, const int* __restrict__ kept_ids,
    const float* __restrict__ kept_vals, float* __restrict__ pmax, float* __restrict__ psum)
{
    int g = blockIdx.x, c = blockIdx.y;
    int tid = threadIdx.x;
    __shared__ int   ids[RCHUNK];
    __shared__ float vals[RCHUNK];
    for (int i = tid; i < RCHUNK; i += 128) {
        ids[i]  = kept_ids[g*KKEEP + c*RCHUNK + i];
        vals[i] = kept_vals[g*KKEEP + c*RCHUNK + i];
    }
    __syncthreads();
    float4 mx = make_float4(-INFINITY,-INFINITY,-INFINITY,-INFINITY);
    float4 sm = make_float4(0.f,0.f,0.f,0.f);
    for (int r = 0; r < RCHUNK; ++r) {
        float4 v = *(const float4*)(x1 + (size_t)ids[r]*HD + tid*4);
        float vl = vals[r];
        v.x *= vl; v.y *= vl; v.z *= vl; v.w *= vl;
        mx.x = fmaxf(mx.x, v.x); mx.y = fmaxf(mx.y, v.y);
        mx.z = fmaxf(mx.z, v.z); mx.w = fmaxf(mx.w, v.w);
        sm.x += v.x; sm.y += v.y; sm.z += v.z; sm.w += v.w;
    }
    *(float4*)(pmax + (size_t)(g*8 + c)*HD + tid*4) = mx;
    *(float4*)(psum + (size_t)(g*8 + c)*HD + tid*4) = sm;
}

// ---------------- finalize pool + MLP head (k-split, 256 threads) ----------------
__global__ __launch_bounds__(256) void mlp_kernel(
    const float* __restrict__ pmax, const float* __restrict__ psum,
    const float* __restrict__ w1, const float* __restrict__ b1,
    const float* __restrict__ w2, const float* __restrict__ b2,
    const float* __restrict__ w3, const float* __restrict__ b3,
    float* __restrict__ out)
{
    int g = blockIdx.x;
    int tid = threadIdx.x; // 256
    __shared__ float sx[1024];
    __shared__ float part1[8][128];
    __shared__ float sh1[128];
    __shared__ float part2[4][64];
    __shared__ float sh2[64];
    __shared__ float part3[8][8];
    __shared__ float slog[8];

    // pool finalize: threads 0..127 -> max cols (float4), 128..255 -> mean cols
    {
        int half = tid >> 7;           // 0 = max, 1 = mean
        int c4 = tid & 127;            // float4 column within 512
        const float* basep = half ? psum : pmax;
        float4 r = *(const float4*)(basep + (size_t)(g*8)*HD + c4*4);
        #pragma unroll
        for (int c = 1; c < 8; ++c) {
            float4 v = *(const float4*)(basep + (size_t)(g*8 + c)*HD + c4*4);
            if (half) { r.x += v.x; r.y += v.y; r.z += v.z; r.w += v.w; }
            else {
                r.x = fmaxf(r.x, v.x); r.y = fmaxf(r.y, v.y);
                r.z = fmaxf(r.z, v.z); r.w = fmaxf(r.w, v.w);
            }
        }
        if (half) { const float inv = 1.0f/KKEEP; r.x *= inv; r.y *= inv; r.z *= inv; r.w *= inv; }
        *(float4*)(sx + half*512 + c4*4) = r;
    }
    __syncthreads();

    // layer 1: 1024 -> 128, split k into 8 slices of 128; thread = (ks, tc), out float4 col tc
    {
        int ks = tid >> 5, tc = tid & 31;
        const float* w1p = w1 + (size_t)(ks*128)*128 + tc*4;
        const float* sxp = sx + ks*128;
        float4 acc = make_float4(0.f,0.f,0.f,0.f);
        #pragma unroll 8
        for (int k = 0; k < 128; ++k) {
            float xk = sxp[k];
            float4 w = *(const float4*)(w1p + (size_t)k*128);
            acc.x = fmaf(xk, w.x, acc.x); acc.y = fmaf(xk, w.y, acc.y);
            acc.z = fmaf(xk, w.z, acc.z); acc.w = fmaf(xk, w.w, acc.w);
        }
        *(float4*)(&part1[ks][tc*4]) = acc;
    }
    __syncthreads();
    if (tid < 128) {
        float s = b1[tid];
        #pragma unroll
        for (int p = 0; p < 8; ++p) s += part1[p][tid];
        sh1[tid] = fmaxf(s, 0.0f);
    }
    __syncthreads();

    // layer 2: 128 -> 64, split k into 4 slices of 32; thread = (ks2, to)
    {
        int ks2 = tid >> 6, to = tid & 63;
        float a = 0.f;
        #pragma unroll 8
        for (int k = 0; k < 32; ++k) {
            int kk = ks2*32 + k;
            a = fmaf(sh1[kk], w2[kk*64 + to], a);
        }
        part2[ks2][to] = a;
    }
    __syncthreads();
    if (tid < 64) {
        float s = b2[tid];
        #pragma unroll
        for (int p = 0; p < 4; ++p) s += part2[p][tid];
        sh2[tid] = fmaxf(s, 0.0f);
    }
    __syncthreads();

    // layer 3: 64 -> 8, split k into 8 slices of 8; thread = (ks3, o)
    if (tid < 64) {
        int ks3 = tid >> 3, o = tid & 7;
        float a = 0.f;
        #pragma unroll
        for (int k = 0; k < 8; ++k) {
            int kk = ks3*8 + k;
            a = fmaf(sh2[kk], w3[kk*8 + o], a);
        }
        part3[ks3][o] = a;
    }
    __syncthreads();
    if (tid < 8) {
        float s = b3[tid];
        #pragma unroll
        for (int p = 0; p < 8; ++p) s += part3[p][tid];
        slog[tid] = s;
    }
    __syncthreads();
    if (tid == 0) {
        float m = slog[0];
        for (int i = 1; i < 8; ++i) m = fmaxf(m, slog[i]);
        float ssum = 0.0f;
        for (int i = 0; i < 8; ++i) ssum += expf(slog[i] - m);
        float lse = m + logf(ssum);
        for (int i = 0; i < 8; ++i) out[g*8 + i] = slog[i] - lse;
    }
}

extern "C" void kernel_launch(void* const* d_in, const int* in_sizes, int n_in,
                              void* d_out, int out_size, void* d_ws, size_t ws_size,
                              hipStream_t stream) {
    const float* x        = (const float*)d_in[0];
    const int*   ei       = (const int*)d_in[1];
    const float* W        = (const float*)d_in[4];
    const float* att_src  = (const float*)d_in[5];
    const float* att_dst  = (const float*)d_in[6];
    const float* bias     = (const float*)d_in[7];
    const float* topk_w   = (const float*)d_in[8];
    const float* w1       = (const float*)d_in[9];
    const float* b1       = (const float*)d_in[10];
    const float* w2       = (const float*)d_in[11];
    const float* b2       = (const float*)d_in[12];
    const float* w3       = (const float*)d_in[13];
    const float* b3       = (const float*)d_in[14];
    float* out = (float*)d_out;

    const int* src = ei;
    const int* dst = ei + E_EDGES;

    char* wsb = (char*)d_ws;
    size_t off = 0;
    auto alloc = [&](size_t bytes) -> void* {
        void* p = (void*)(wsb + off);
        off += (bytes + 255) & ~(size_t)255;
        return p;
    };
    float* h        = (float*)alloc((size_t)N_NODES*HD*4);
    float* x1       = (float*)alloc((size_t)N_NODES*HD*4);
    float* a_s      = (float*)alloc((size_t)N_NODES*4*4);
    float* a_d      = (float*)alloc((size_t)N_NODES*4*4);
    float* Ws       = (float*)alloc(F_IN*4*4);
    float* Wd       = (float*)alloc(F_IN*4*4);
    float* misc     = (float*)alloc(256);
    int*   counts   = (int*)alloc((size_t)N_NODES*4);
    int*   slots    = (int*)alloc((size_t)N_NODES*CAP*4);
    float* scores   = (float*)alloc((size_t)N_NODES*4);
    int*   kept_ids = (int*)alloc((size_t)B_GRAPHS*KKEEP*4);
    float* kept_vals= (float*)alloc((size_t)B_GRAPHS*KKEEP*4);
    float* pmax     = (float*)alloc((size_t)B_GRAPHS*8*HD*4);
    float* psum     = (float*)alloc((size_t)B_GRAPHS*8*HD*4);

    hipMemsetAsync(counts, 0, (size_t)N_NODES*4, stream);
    prep_kernel<<<1, 256, 0, stream>>>(W, att_src, att_dst, topk_w, Ws, Wd, misc);
    compute_h_kernel<<<N_NODES/NPB, 256, 0, stream>>>(x, W, Ws, Wd, h, a_s, a_d);
    build_slots_kernel<<<640, 256, 0, stream>>>(dst, counts, slots);
    gat_agg_kernel<<<N_NODES/4, 256, 0, stream>>>(h, a_s, a_d, counts, slots, src,
                                                  bias, topk_w, misc, x1, scores);
    topk_kernel<<<dim3(B_GRAPHS, 4), 256, 0, stream>>>(scores, kept_ids, kept_vals);
    pool_partial_kernel<<<dim3(B_GRAPHS, 8), 128, 0, stream>>>(x1, kept_ids, kept_vals, pmax, psum);
    mlp_kernel<<<B_GRAPHS, 256, 0, stream>>>(pmax, psum, w1, b1, w2, b2, w3, b3, out);
}